// Round 17
// baseline (32.376 us; speedup 1.0000x reference)
//
#include <hip/hip_runtime.h>
#include <float.h>

#define NPTS   8192
#define NB     4
#define NBDIR  (NB * 2)             // 8 (batch, direction) pairs
#define BLKF   512                  // fused kernel: 8 waves
#define QPW    32                   // one 32-query MFMA tile per wave
#define QPB    (4 * QPW)            // 128 queries per block (4 tiles x 2 replicas)
#define NQB    (NPTS / QPB)         // 64 query blocks per bd
#define STAGE  1024                 // source points per LDS stage (32 KB packed)
#define NSTAGE (NPTS / STAGE)       // 8 stages: block sweeps ALL sources
#define HALF   512                  // sources per replica per stage
#define BLK    256                  // final/fallback block

typedef __attribute__((ext_vector_type(8)))  short          short8;
typedef __attribute__((ext_vector_type(8)))  unsigned short ushort8;
typedef __attribute__((ext_vector_type(16))) float          f32x16;

__device__ inline unsigned short f2bf(float x) {           // RNE f32 -> bf16
  unsigned u = __builtin_bit_cast(unsigned, x);
  u = u + 0x7FFFu + ((u >> 16) & 1u);
  return (unsigned short)(u >> 16);
}
__device__ inline float bf2f(unsigned short h) {
  unsigned u = ((unsigned)h) << 16;
  return __builtin_bit_cast(float, u);
}

// K=16 split packing:
//   A row (both halves identical): [hx,hy,hz,lx,ly,lz,1,0]
//   B lo half: [-2hx,-2hy,-2hz,-2hx,-2hy,-2hz,s2h,0]
//   B hi half: [-2lx,-2ly,-2lz,-2lx,-2ly,-2lz,s2l,0]
// sum_k A[q][k]*B[s][k] = -2*(q.s) + |s|^2, every bf16 product exact in f32.
__device__ inline ushort8 pack_arow(float x, float y, float z) {
  unsigned short hx = f2bf(x), hy = f2bf(y), hz = f2bf(z);
  unsigned short lx = f2bf(x - bf2f(hx)), ly = f2bf(y - bf2f(hy)),
                 lz = f2bf(z - bf2f(hz));
  ushort8 a = {hx, hy, hz, lx, ly, lz, (unsigned short)0x3F80, 0};
  return a;
}
__device__ inline void pack_brow(float x, float y, float z,
                                 ushort8* blo, ushort8* bhi) {
  unsigned short hx = f2bf(x), hy = f2bf(y), hz = f2bf(z);
  float fx = bf2f(hx), fy = bf2f(hy), fz = bf2f(hz);
  unsigned short lx = f2bf(x - fx), ly = f2bf(y - fy), lz = f2bf(z - fz);
  float s2 = fmaf(x, x, fmaf(y, y, z * z));
  unsigned short s2h = f2bf(s2);
  unsigned short s2l = f2bf(s2 - bf2f(s2h));
  unsigned short nhx = f2bf(-2.0f * fx), nhy = f2bf(-2.0f * fy),
                 nhz = f2bf(-2.0f * fz);
  unsigned short nlx = f2bf(-2.0f * bf2f(lx)), nly = f2bf(-2.0f * bf2f(ly)),
                 nlz = f2bf(-2.0f * bf2f(lz));
  ushort8 lo = {nhx, nhy, nhz, nhx, nhy, nhz, s2h, 0};
  ushort8 hi = {nlx, nly, nlz, nlx, nly, nlz, s2l, 0};
  *blo = lo; *bhi = hi;
}

// Fused main with SOURCE-REPLICA split: 8 waves = 2 replicas x 4 query tiles.
// Replica r sweeps source half r of each staged chunk (R15 was latency-bound
// at 31% issue utilization with 2 waves/SIMD; this doubles waves per query
// to 4/SIMD with identical total work and staging). Inner body is R15's
// measured-best: 1 ds_read_b128 + 1 builtin MFMA + 16 single-d-operand fmin.
// End: replica 1 dumps m[16] to the freed staging LDS; replica 0 fmins and
// runs the epilogue. Grid 512 = bd(8) x qblk(64); 2 blocks/CU.
// Fragment maps: A row=l&31, B col=l&31 (k-half via l>>5, order-invariant
// because A's two k-halves are identical); C/D (verified m74/m101):
// col=l&31, row=(reg&3)+8*(reg>>2)+4*(l>>5).
__global__ __launch_bounds__(BLKF) void chamfer_fused_kernel(
    const float* __restrict__ tpl, const float* __restrict__ src,
    float* __restrict__ partial) {
  __shared__ ushort8 blds8[2 * STAGE];    // 32 KB (staging, then min-combine)
  __shared__ float red[8];
  const int bd   = blockIdx.x & 7;        // one bd per XCD slot
  const int qblk = blockIdx.x >> 3;
  const int t = threadIdx.x, w = t >> 6, l = t & 63;
  const int tile = w & 3, rep = w >> 2;
  const int b = bd >> 1, dir = bd & 1;
  const int qbase = qblk * QPB + tile * QPW;

  const float* qraw = (dir ? src : tpl) + (size_t)b * NPTS * 3;  // queries
  const float* sraw = (dir ? tpl : src) + (size_t)b * NPTS * 3;  // sources

  // A fragment packed in-register (one 32-query tile per wave).
  short8 a0;
  {
    int q0 = qbase + (l & 31);
    a0 = __builtin_bit_cast(short8,
        pack_arow(qraw[3 * q0], qraw[3 * q0 + 1], qraw[3 * q0 + 2]));
  }

  f32x16 m0;
  #pragma unroll
  for (int j = 0; j < 16; ++j) m0[j] = FLT_MAX;
  const f32x16 zero = {0.f, 0.f, 0.f, 0.f, 0.f, 0.f, 0.f, 0.f,
                       0.f, 0.f, 0.f, 0.f, 0.f, 0.f, 0.f, 0.f};

  for (int sg = 0; sg < NSTAGE; ++sg) {
    if (sg) __syncthreads();
    // Stage 1024 source points with fused f32 -> split-bf16 packing.
    #pragma unroll
    for (int i = 0; i < STAGE / BLKF; ++i) {  // 2 pts per thread
      int idx = t + BLKF * i;
      int p = sg * STAGE + idx;
      ushort8 blo, bhi;
      pack_brow(sraw[3 * p], sraw[3 * p + 1], sraw[3 * p + 2], &blo, &bhi);
      blds8[idx]         = blo;           // lo plane
      blds8[STAGE + idx] = bhi;           // hi plane
    }
    __syncthreads();

    // Replica r consumes sources [r*512, r*512+512) of this stage.
    const int rb = (l >> 5) * STAGE + (l & 31) + rep * HALF;
    #pragma unroll 4
    for (int st = 0; st < HALF / 32; ++st) {   // 16 iters per stage
      short8 bf = __builtin_bit_cast(short8, blds8[rb + st * 32]);
      f32x16 d0 = __builtin_amdgcn_mfma_f32_32x32x16_bf16(a0, bf, zero, 0, 0, 0);
      #pragma unroll
      for (int j = 0; j < 16; ++j) m0[j] = fminf(m0[j], d0[j]);
    }
  }

  // Cross-replica elementwise min through the freed staging LDS.
  __syncthreads();                        // all staging reads done
  float* scratch = (float*)blds8;         // 4 tiles x 64 lanes x 16 f32 = 16 KB
  if (rep == 1) {
    #pragma unroll
    for (int j = 0; j < 16; ++j)
      scratch[(tile * 64 + l) * 16 + j] = m0[j];
  }
  __syncthreads();
  if (rep == 0) {
    #pragma unroll
    for (int j = 0; j < 16; ++j)
      m0[j] = fminf(m0[j], scratch[(tile * 64 + l) * 16 + j]);

    // Min over the 32 source-columns (lanes within each 32-lane group).
    #pragma unroll
    for (int off = 1; off <= 16; off <<= 1) {
      #pragma unroll
      for (int j = 0; j < 16; ++j)
        m0[j] = fminf(m0[j], __shfl_xor(m0[j], off, 64));
    }

    // Lanes 0 and 32 hold 16 query-rows each; add |q|^2 and sum.
    if ((l & 31) == 0) {
      const int radd = (l >> 5) * 4;
      float lsum = 0.0f;
      #pragma unroll
      for (int r = 0; r < 16; ++r) {
        int row = (r & 3) + 8 * (r >> 2) + radd;
        int q = qbase + row;
        float x = qraw[3 * q], y = qraw[3 * q + 1], z = qraw[3 * q + 2];
        lsum += m0[r] + fmaf(x, x, fmaf(y, y, z * z));
      }
      red[tile * 2 + (l >> 5)] = lsum;
    }
  }
  __syncthreads();
  if (t == 0) {
    float s = 0.0f;
    #pragma unroll
    for (int i = 0; i < 8; ++i) s += red[i];
    partial[blockIdx.x] = s;
  }
}

// Final: fixed-order sum of 512 partials; mean over 2*B*N = 32768 mins.
__global__ __launch_bounds__(BLK) void final512_kernel(
    const float* __restrict__ partial, float* __restrict__ out) {
  __shared__ float wsum[BLK / 64];
  int t = threadIdx.x;
  float v = partial[t] + partial[t + 256];
  #pragma unroll
  for (int off = 32; off > 0; off >>= 1) v += __shfl_down(v, off, 64);
  if ((t & 63) == 0) wsum[t >> 6] = v;
  __syncthreads();
  if (t == 0)
    out[0] = (wsum[0] + wsum[1] + wsum[2] + wsum[3]) * (1.0f / 32768.0f);
}

// ---------------- fallback (R2-style) if ws is too small --------------------
#define TILE   2048
#define NTILES (NPTS / TILE)
#define QBLKS  (NPTS / BLK)

__global__ __launch_bounds__(BLK) void chamfer_min_kernel(
    const float* __restrict__ tpl, const float* __restrict__ src,
    float* __restrict__ partial) {
  __shared__ float4 s4[TILE];
  __shared__ float wsum[BLK / 64];
  const int b = blockIdx.z, dir = blockIdx.y;
  const float* qb = (dir == 0 ? tpl : src) + (size_t)b * NPTS * 3;
  const float* rb = (dir == 0 ? src : tpl) + (size_t)b * NPTS * 3;
  const int t = threadIdx.x;
  const int q = blockIdx.x * BLK + t;
  const float qx = qb[3 * q + 0], qy = qb[3 * q + 1], qz = qb[3 * q + 2];
  const float q2 = fmaf(qx, qx, fmaf(qy, qy, qz * qz));
  float b0 = FLT_MAX, b1 = FLT_MAX;
  for (int tile = 0; tile < NTILES; ++tile) {
    const float* rt = rb + 3 * TILE * tile;
    #pragma unroll
    for (int k = 0; k < TILE / BLK; ++k) {
      int p = t + BLK * k;
      float x = rt[3 * p + 0], y = rt[3 * p + 1], z = rt[3 * p + 2];
      s4[p] = make_float4(-2.0f * x, -2.0f * y, -2.0f * z,
                          fmaf(x, x, fmaf(y, y, z * z)));
    }
    __syncthreads();
    #pragma unroll 2
    for (int m = 0; m < TILE; m += 2) {
      float4 p0 = s4[m + 0], p1 = s4[m + 1];
      float d0 = fmaf(qx, p0.x, fmaf(qy, p0.y, fmaf(qz, p0.z, p0.w)));
      float d1 = fmaf(qx, p1.x, fmaf(qy, p1.y, fmaf(qz, p1.z, p1.w)));
      b0 = fminf(b0, fminf(d0, d1));
      b1 = fminf(b1, d0);
    }
    __syncthreads();
  }
  float best = fminf(b0, b1) + q2;
  float v = best;
  #pragma unroll
  for (int off = 32; off > 0; off >>= 1) v += __shfl_down(v, off, 64);
  if ((t & 63) == 0) wsum[t >> 6] = v;
  __syncthreads();
  if (t == 0)
    partial[((b * 2 + dir) * QBLKS) + blockIdx.x] =
        wsum[0] + wsum[1] + wsum[2] + wsum[3];
}

__global__ __launch_bounds__(BLK) void final256_kernel(
    const float* __restrict__ partial, float* __restrict__ out) {
  __shared__ float wsum[BLK / 64];
  int t = threadIdx.x;
  float v = partial[t];
  #pragma unroll
  for (int off = 32; off > 0; off >>= 1) v += __shfl_down(v, off, 64);
  if ((t & 63) == 0) wsum[t >> 6] = v;
  __syncthreads();
  if (t == 0)
    out[0] = (wsum[0] + wsum[1] + wsum[2] + wsum[3]) * (1.0f / 32768.0f);
}

// ----------------------------------------------------------------------------
extern "C" void kernel_launch(void* const* d_in, const int* in_sizes, int n_in,
                              void* d_out, int out_size, void* d_ws, size_t ws_size,
                              hipStream_t stream) {
  const float* tpl = (const float*)d_in[0];   // template (4, 8192, 3) f32
  const float* src = (const float*)d_in[1];   // source   (4, 8192, 3) f32
  float* out = (float*)d_out;
  float* partial = (float*)d_ws;

  if (ws_size >= 512 * sizeof(float)) {
    chamfer_fused_kernel<<<NBDIR * NQB, BLKF, 0, stream>>>(tpl, src, partial);
    final512_kernel<<<1, BLK, 0, stream>>>(partial, out);
  } else {
    dim3 grid(QBLKS, 2, NB);
    chamfer_min_kernel<<<grid, BLK, 0, stream>>>(tpl, src, partial);
    final256_kernel<<<1, BLK, 0, stream>>>(partial, out);
  }
}

// Round 18
// 30.282 us; speedup vs baseline: 1.0692x; 1.0692x over previous
//
#include <hip/hip_runtime.h>
#include <float.h>

#define NPTS   8192
#define NB     4
#define NBDIR  (NB * 2)             // 8 (batch, direction) pairs
#define BLKF   512                  // fused kernel: 8 waves
#define QPW    32                   // one 32-query MFMA tile per wave
#define QPB    (8 * QPW)            // 256 queries per block
#define NQB    (NPTS / QPB)         // 32 query blocks per bd
#define STAGE  1024                 // source points per LDS stage (32 KB packed)
#define NSTAGE (NPTS / STAGE)       // 8 stages: block sweeps ALL sources
#define BLK    256                  // final/fallback block

typedef __attribute__((ext_vector_type(8)))  short          short8;
typedef __attribute__((ext_vector_type(8)))  unsigned short ushort8;
typedef __attribute__((ext_vector_type(16))) float          f32x16;

__device__ inline unsigned short f2bf(float x) {           // RNE f32 -> bf16
  unsigned u = __builtin_bit_cast(unsigned, x);
  u = u + 0x7FFFu + ((u >> 16) & 1u);
  return (unsigned short)(u >> 16);
}
__device__ inline float bf2f(unsigned short h) {
  unsigned u = ((unsigned)h) << 16;
  return __builtin_bit_cast(float, u);
}

// K=16 split packing:
//   A row (both halves identical): [hx,hy,hz,lx,ly,lz,1,0]
//   B lo half: [-2hx,-2hy,-2hz,-2hx,-2hy,-2hz,s2h,0]
//   B hi half: [-2lx,-2ly,-2lz,-2lx,-2ly,-2lz,s2l,0]
// sum_k A[q][k]*B[s][k] = -2*(q.s) + |s|^2, every bf16 product exact in f32.
__device__ inline ushort8 pack_arow(float x, float y, float z) {
  unsigned short hx = f2bf(x), hy = f2bf(y), hz = f2bf(z);
  unsigned short lx = f2bf(x - bf2f(hx)), ly = f2bf(y - bf2f(hy)),
                 lz = f2bf(z - bf2f(hz));
  ushort8 a = {hx, hy, hz, lx, ly, lz, (unsigned short)0x3F80, 0};
  return a;
}
__device__ inline void pack_brow(float x, float y, float z,
                                 ushort8* blo, ushort8* bhi) {
  unsigned short hx = f2bf(x), hy = f2bf(y), hz = f2bf(z);
  float fx = bf2f(hx), fy = bf2f(hy), fz = bf2f(hz);
  unsigned short lx = f2bf(x - fx), ly = f2bf(y - fy), lz = f2bf(z - fz);
  float s2 = fmaf(x, x, fmaf(y, y, z * z));
  unsigned short s2h = f2bf(s2);
  unsigned short s2l = f2bf(s2 - bf2f(s2h));
  unsigned short nhx = f2bf(-2.0f * fx), nhy = f2bf(-2.0f * fy),
                 nhz = f2bf(-2.0f * fz);
  unsigned short nlx = f2bf(-2.0f * bf2f(lx)), nly = f2bf(-2.0f * bf2f(ly)),
                 nlz = f2bf(-2.0f * bf2f(lz));
  ushort8 lo = {nhx, nhy, nhz, nhx, nhy, nhz, s2h, 0};
  ushort8 hi = {nlx, nly, nlz, nlx, nly, nlz, s2l, 0};
  *blo = lo; *bhi = hi;
}

// Fused main (R15, measured best: 30.2 us total): query-only grid split ->
// per-query min completes IN-BLOCK (no cand/combine). 256 blocks of 512
// threads (8 waves x 32 queries), each sweeps all 8192 sources in 8 staged
// LDS chunks with fused f32->split-bf16 packing. Per iter: 1 ds_read_b128 +
// 1 MFMA + 16 single-d-operand fminf (two-d-operand min3 regressed R7-R9,
// R16; occupancy/latency levers null R12/R13/R17).
// Fragment maps: A row=l&31, B col=l&31 (k-half via l>>5, order-invariant
// because A's two k-halves are identical); C/D (verified m74/m101):
// col=l&31, row=(reg&3)+8*(reg>>2)+4*(l>>5).
__global__ __launch_bounds__(BLKF) void chamfer_fused_kernel(
    const float* __restrict__ tpl, const float* __restrict__ src,
    float* __restrict__ partial) {
  __shared__ ushort8 blds8[2 * STAGE];    // 32 KB
  __shared__ float red[16];
  const int bd   = blockIdx.x & 7;        // one bd per XCD slot
  const int qblk = blockIdx.x >> 3;
  const int t = threadIdx.x, w = t >> 6, l = t & 63;
  const int b = bd >> 1, dir = bd & 1;
  const int qbase = qblk * QPB + w * QPW;

  const float* qraw = (dir ? src : tpl) + (size_t)b * NPTS * 3;  // queries
  const float* sraw = (dir ? tpl : src) + (size_t)b * NPTS * 3;  // sources

  // A fragment packed in-register (one 32-query tile per wave).
  short8 a0;
  {
    int q0 = qbase + (l & 31);
    a0 = __builtin_bit_cast(short8,
        pack_arow(qraw[3 * q0], qraw[3 * q0 + 1], qraw[3 * q0 + 2]));
  }

  f32x16 m0;
  #pragma unroll
  for (int j = 0; j < 16; ++j) m0[j] = FLT_MAX;
  const f32x16 zero = {0.f, 0.f, 0.f, 0.f, 0.f, 0.f, 0.f, 0.f,
                       0.f, 0.f, 0.f, 0.f, 0.f, 0.f, 0.f, 0.f};

  for (int sg = 0; sg < NSTAGE; ++sg) {
    if (sg) __syncthreads();
    // Stage 1024 source points with fused f32 -> split-bf16 packing.
    #pragma unroll
    for (int i = 0; i < STAGE / BLKF; ++i) {  // 2 pts per thread
      int idx = t + BLKF * i;
      int p = sg * STAGE + idx;
      ushort8 blo, bhi;
      pack_brow(sraw[3 * p], sraw[3 * p + 1], sraw[3 * p + 2], &blo, &bhi);
      blds8[idx]         = blo;           // lo plane
      blds8[STAGE + idx] = bhi;           // hi plane
    }
    __syncthreads();

    const int rb = (l >> 5) * STAGE + (l & 31);
    #pragma unroll 4
    for (int st = 0; st < STAGE / 32; ++st) {   // 32 iters per stage
      short8 bf = __builtin_bit_cast(short8, blds8[rb + st * 32]);
      f32x16 d0 = __builtin_amdgcn_mfma_f32_32x32x16_bf16(a0, bf, zero, 0, 0, 0);
      #pragma unroll
      for (int j = 0; j < 16; ++j) m0[j] = fminf(m0[j], d0[j]);
    }
  }

  // Min over the 32 source-columns (lanes within each 32-lane group).
  #pragma unroll
  for (int off = 1; off <= 16; off <<= 1) {
    #pragma unroll
    for (int j = 0; j < 16; ++j)
      m0[j] = fminf(m0[j], __shfl_xor(m0[j], off, 64));
  }

  // Lanes 0 and 32 hold 16 query-rows each; add |q|^2 and sum (per-lane).
  float lsum = 0.0f;
  if ((l & 31) == 0) {
    const int radd = (l >> 5) * 4;
    #pragma unroll
    for (int r = 0; r < 16; ++r) {
      int row = (r & 3) + 8 * (r >> 2) + radd;
      int q = qbase + row;
      float x = qraw[3 * q], y = qraw[3 * q + 1], z = qraw[3 * q + 2];
      lsum += m0[r] + fmaf(x, x, fmaf(y, y, z * z));
    }
    red[w * 2 + (l >> 5)] = lsum;
  }
  __syncthreads();
  if (t == 0) {
    float s = 0.0f;
    #pragma unroll
    for (int i = 0; i < 16; ++i) s += red[i];
    partial[blockIdx.x] = s;
  }
}

// Final: fixed-order sum of 256 partials; mean over 2*B*N = 32768 mins.
__global__ __launch_bounds__(BLK) void final256_kernel(
    const float* __restrict__ partial, float* __restrict__ out) {
  __shared__ float wsum[BLK / 64];
  int t = threadIdx.x;
  float v = partial[t];
  #pragma unroll
  for (int off = 32; off > 0; off >>= 1) v += __shfl_down(v, off, 64);
  if ((t & 63) == 0) wsum[t >> 6] = v;
  __syncthreads();
  if (t == 0)
    out[0] = (wsum[0] + wsum[1] + wsum[2] + wsum[3]) * (1.0f / 32768.0f);
}

// ---------------- fallback (R2-style) if ws is too small --------------------
#define TILE   2048
#define NTILES (NPTS / TILE)
#define QBLKS  (NPTS / BLK)

__global__ __launch_bounds__(BLK) void chamfer_min_kernel(
    const float* __restrict__ tpl, const float* __restrict__ src,
    float* __restrict__ partial) {
  __shared__ float4 s4[TILE];
  __shared__ float wsum[BLK / 64];
  const int b = blockIdx.z, dir = blockIdx.y;
  const float* qb = (dir == 0 ? tpl : src) + (size_t)b * NPTS * 3;
  const float* rb = (dir == 0 ? src : tpl) + (size_t)b * NPTS * 3;
  const int t = threadIdx.x;
  const int q = blockIdx.x * BLK + t;
  const float qx = qb[3 * q + 0], qy = qb[3 * q + 1], qz = qb[3 * q + 2];
  const float q2 = fmaf(qx, qx, fmaf(qy, qy, qz * qz));
  float b0 = FLT_MAX, b1 = FLT_MAX;
  for (int tile = 0; tile < NTILES; ++tile) {
    const float* rt = rb + 3 * TILE * tile;
    #pragma unroll
    for (int k = 0; k < TILE / BLK; ++k) {
      int p = t + BLK * k;
      float x = rt[3 * p + 0], y = rt[3 * p + 1], z = rt[3 * p + 2];
      s4[p] = make_float4(-2.0f * x, -2.0f * y, -2.0f * z,
                          fmaf(x, x, fmaf(y, y, z * z)));
    }
    __syncthreads();
    #pragma unroll 2
    for (int m = 0; m < TILE; m += 2) {
      float4 p0 = s4[m + 0], p1 = s4[m + 1];
      float d0 = fmaf(qx, p0.x, fmaf(qy, p0.y, fmaf(qz, p0.z, p0.w)));
      float d1 = fmaf(qx, p1.x, fmaf(qy, p1.y, fmaf(qz, p1.z, p1.w)));
      b0 = fminf(b0, fminf(d0, d1));
      b1 = fminf(b1, d0);
    }
    __syncthreads();
  }
  float best = fminf(b0, b1) + q2;
  float v = best;
  #pragma unroll
  for (int off = 32; off > 0; off >>= 1) v += __shfl_down(v, off, 64);
  if ((t & 63) == 0) wsum[t >> 6] = v;
  __syncthreads();
  if (t == 0)
    partial[((b * 2 + dir) * QBLKS) + blockIdx.x] =
        wsum[0] + wsum[1] + wsum[2] + wsum[3];
}

// ----------------------------------------------------------------------------
extern "C" void kernel_launch(void* const* d_in, const int* in_sizes, int n_in,
                              void* d_out, int out_size, void* d_ws, size_t ws_size,
                              hipStream_t stream) {
  const float* tpl = (const float*)d_in[0];   // template (4, 8192, 3) f32
  const float* src = (const float*)d_in[1];   // source   (4, 8192, 3) f32
  float* out = (float*)d_out;
  float* partial = (float*)d_ws;              // 256 floats

  if (ws_size >= 256 * sizeof(float)) {
    chamfer_fused_kernel<<<NBDIR * NQB, BLKF, 0, stream>>>(tpl, src, partial);
    final256_kernel<<<1, BLK, 0, stream>>>(partial, out);
  } else {
    dim3 grid(QBLKS, 2, NB);
    chamfer_min_kernel<<<grid, BLK, 0, stream>>>(tpl, src, partial);
    final256_kernel<<<1, BLK, 0, stream>>>(partial, out);
  }
}